// Round 1
// baseline (106.738 us; speedup 1.0000x reference)
//
#include <hip/hip_runtime.h>
#include <math.h>

#define BB 512      // batch
#define TT 512      // seq len
#define DD 1024     // d_model
#define NF 256      // n_features
#define DE 256      // d_feat_emb
#define DH 512      // d_hidden
#define KK 64       // proto_num
#define PD 1024     // proto_dim
#define IN_DIM (DD + DE)   // 1280
#define SPLIT 4

// ---------------------------------------------------------------------------
// Kernel 1: masked partial sums of feat over t ranges. grid (B, SPLIT), 256 thr
// part[q][b][f] = sum_{t in [q*len/4,(q+1)*len/4)} feat[b,t,f]
// ---------------------------------------------------------------------------
__global__ __launch_bounds__(256) void feat_partial_kernel(
    const float* __restrict__ feat, const int* __restrict__ isl,
    float* __restrict__ part) {
  int b = blockIdx.x;
  int q = blockIdx.y;
  int len = isl[b];
  len = len < 1 ? 1 : (len > TT ? TT : len);
  int lo = (q * len) / SPLIT;
  int hi = ((q + 1) * len) / SPLIT;
  int wave = threadIdx.x >> 6;
  int lane = threadIdx.x & 63;
  const float* fb = feat + (size_t)b * TT * NF;

  float4 a0 = {0.f, 0.f, 0.f, 0.f}, a1 = a0, a2 = a0, a3 = a0;
  int t = lo + wave;
  for (; t + 12 < hi; t += 16) {
    float4 v0 = *(const float4*)(fb + (size_t)t * NF + lane * 4);
    float4 v1 = *(const float4*)(fb + (size_t)(t + 4) * NF + lane * 4);
    float4 v2 = *(const float4*)(fb + (size_t)(t + 8) * NF + lane * 4);
    float4 v3 = *(const float4*)(fb + (size_t)(t + 12) * NF + lane * 4);
    a0.x += v0.x; a0.y += v0.y; a0.z += v0.z; a0.w += v0.w;
    a1.x += v1.x; a1.y += v1.y; a1.z += v1.z; a1.w += v1.w;
    a2.x += v2.x; a2.y += v2.y; a2.z += v2.z; a2.w += v2.w;
    a3.x += v3.x; a3.y += v3.y; a3.z += v3.z; a3.w += v3.w;
  }
  for (; t < hi; t += 4) {
    float4 v0 = *(const float4*)(fb + (size_t)t * NF + lane * 4);
    a0.x += v0.x; a0.y += v0.y; a0.z += v0.z; a0.w += v0.w;
  }
  float4 acc;
  acc.x = a0.x + a1.x + a2.x + a3.x;
  acc.y = a0.y + a1.y + a2.y + a3.y;
  acc.z = a0.z + a1.z + a2.z + a3.z;
  acc.w = a0.w + a1.w + a2.w + a3.w;

  __shared__ float red[4][NF];
  *(float4*)&red[wave][lane * 4] = acc;
  __syncthreads();
  int f = threadIdx.x;
  float s = red[0][f] + red[1][f] + red[2][f] + red[3][f];
  part[((size_t)q * BB + b) * NF + f] = s;
}

// ---------------------------------------------------------------------------
// Kernel 2: per-b pooled vector: [h_last (1024) | f_emb (256)]. grid B, 256 thr
// ---------------------------------------------------------------------------
__global__ __launch_bounds__(256) void pooled_kernel(
    const float* __restrict__ hidden, const int* __restrict__ isl,
    const float* __restrict__ part, const float* __restrict__ Wf,
    const float* __restrict__ bf, float* __restrict__ pooled) {
  int b = blockIdx.x;
  int tid = threadIdx.x;
  int len = isl[b];
  len = len < 1 ? 1 : (len > TT ? TT : len);

  __shared__ float sm[NF];
  float s = part[((size_t)0 * BB + b) * NF + tid] +
            part[((size_t)1 * BB + b) * NF + tid] +
            part[((size_t)2 * BB + b) * NF + tid] +
            part[((size_t)3 * BB + b) * NF + tid];
  sm[tid] = s / (float)len;

  // gather last hidden state (coalesced float4 copy)
  const float* hl = hidden + (size_t)b * TT * DD + (size_t)(len - 1) * DD;
  float4 v = *(const float4*)(hl + tid * 4);
  *(float4*)(pooled + (size_t)b * IN_DIM + tid * 4) = v;

  __syncthreads();

  // f_emb[j] = sum_i f_mean[i] * Wf[i][j] + bf[j]
  float acc = bf[tid];
#pragma unroll 4
  for (int i = 0; i < NF; ++i) acc += sm[i] * Wf[i * DE + tid];
  pooled[(size_t)b * IN_DIM + DD + tid] = acc;
}

// ---------------------------------------------------------------------------
// Kernel 3: h = gelu(pooled @ W1 + b1). fp32 tiled GEMM 32x32x32, 2x2/thread.
// grid (DH/32, B/32), 256 thr
// ---------------------------------------------------------------------------
__device__ __forceinline__ float gelu_exact(float x) {
  return 0.5f * x * (1.0f + erff(x * 0.70710678118654752440f));
}

__global__ __launch_bounds__(256) void gemm_gelu_kernel(
    const float* __restrict__ pooled, const float* __restrict__ W1,
    const float* __restrict__ b1, float* __restrict__ h) {
  __shared__ float As[32][36];  // transposed: As[k][row]
  __shared__ float Bs[32][36];  // Bs[k][col]
  int bx = blockIdx.x;  // N tile
  int by = blockIdx.y;  // M tile
  int tid = threadIdx.x;
  int tx = tid & 15;    // col pair
  int ty = tid >> 4;    // row pair
  int lr = tid >> 3;        // load row 0..31
  int lc = (tid & 7) * 4;   // load col x4

  const float* Ab = pooled + (size_t)(by * 32) * IN_DIM;
  const float* Bb = W1 + bx * 32;
  float acc00 = 0.f, acc01 = 0.f, acc10 = 0.f, acc11 = 0.f;

  for (int k0 = 0; k0 < IN_DIM; k0 += 32) {
    float4 av = *(const float4*)(Ab + (size_t)lr * IN_DIM + k0 + lc);
    float4 bv = *(const float4*)(Bb + (size_t)(k0 + lr) * DH + lc);
    As[lc + 0][lr] = av.x;
    As[lc + 1][lr] = av.y;
    As[lc + 2][lr] = av.z;
    As[lc + 3][lr] = av.w;
    *(float4*)&Bs[lr][lc] = bv;
    __syncthreads();
#pragma unroll
    for (int kk = 0; kk < 32; ++kk) {
      float2 a = *(float2*)&As[kk][ty * 2];
      float2 bq = *(float2*)&Bs[kk][tx * 2];
      acc00 += a.x * bq.x;
      acc01 += a.x * bq.y;
      acc10 += a.y * bq.x;
      acc11 += a.y * bq.y;
    }
    __syncthreads();
  }
  int row = by * 32 + ty * 2;
  int col = bx * 32 + tx * 2;
  float bi0 = b1[col], bi1 = b1[col + 1];
  h[(size_t)row * DH + col]           = gelu_exact(acc00 + bi0);
  h[(size_t)row * DH + col + 1]       = gelu_exact(acc01 + bi1);
  h[(size_t)(row + 1) * DH + col]     = gelu_exact(acc10 + bi0);
  h[(size_t)(row + 1) * DH + col + 1] = gelu_exact(acc11 + bi1);
}

// ---------------------------------------------------------------------------
// Kernel 4: logits = h @ W2 + b2; top-4 softmax gating; context = w @ proto.
// grid B, 64 thr (one wave per b; lane j owns logit j)
// ---------------------------------------------------------------------------
__global__ __launch_bounds__(64) void head_kernel(
    const float* __restrict__ h, const float* __restrict__ W2,
    const float* __restrict__ b2, const float* __restrict__ proto,
    float* __restrict__ weights, float* __restrict__ logits_out,
    float* __restrict__ context) {
  int b = blockIdx.x;
  int lane = threadIdx.x;

  __shared__ float hs[DH];
  {
    float4 v0 = *(const float4*)(h + (size_t)b * DH + lane * 4);
    float4 v1 = *(const float4*)(h + (size_t)b * DH + 256 + lane * 4);
    *(float4*)&hs[lane * 4] = v0;
    *(float4*)&hs[256 + lane * 4] = v1;
  }
  __syncthreads();

  float acc = b2[lane];
#pragma unroll 8
  for (int i = 0; i < DH; ++i) acc += hs[i] * W2[i * KK + lane];
  logits_out[(size_t)b * KK + lane] = acc;  // TEMP == 1.0

  // top-4 (desc values, ties -> lower index first, matching jax.lax.top_k)
  float cur = acc;
  float tv[4];
  int ti[4];
#pragma unroll
  for (int r = 0; r < 4; ++r) {
    float mv = cur;
    int mi = lane;
#pragma unroll
    for (int off = 32; off; off >>= 1) {
      float ov = __shfl_xor(mv, off);
      int oi = __shfl_xor(mi, off);
      if (ov > mv || (ov == mv && oi < mi)) { mv = ov; mi = oi; }
    }
    tv[r] = mv;
    ti[r] = mi;
    if (lane == mi) cur = -INFINITY;
  }
  float m = tv[0];
  float e0 = expf(tv[0] - m), e1 = expf(tv[1] - m);
  float e2 = expf(tv[2] - m), e3 = expf(tv[3] - m);
  float inv = 1.0f / (e0 + e1 + e2 + e3);
  float w0 = e0 * inv, w1 = e1 * inv, w2 = e2 * inv, w3 = e3 * inv;

  float wt = 0.f;
  if (lane == ti[0]) wt = w0;
  else if (lane == ti[1]) wt = w1;
  else if (lane == ti[2]) wt = w2;
  else if (lane == ti[3]) wt = w3;
  weights[(size_t)b * KK + lane] = wt;

  const float* p0 = proto + (size_t)ti[0] * PD;
  const float* p1 = proto + (size_t)ti[1] * PD;
  const float* p2 = proto + (size_t)ti[2] * PD;
  const float* p3 = proto + (size_t)ti[3] * PD;
#pragma unroll
  for (int q2 = 0; q2 < 4; ++q2) {
    int off = q2 * 256 + lane * 4;
    float4 r0 = *(const float4*)(p0 + off);
    float4 r1 = *(const float4*)(p1 + off);
    float4 r2 = *(const float4*)(p2 + off);
    float4 r3 = *(const float4*)(p3 + off);
    float4 o;
    o.x = w0 * r0.x + w1 * r1.x + w2 * r2.x + w3 * r3.x;
    o.y = w0 * r0.y + w1 * r1.y + w2 * r2.y + w3 * r3.y;
    o.z = w0 * r0.z + w1 * r1.z + w2 * r2.z + w3 * r3.z;
    o.w = w0 * r0.w + w1 * r1.w + w2 * r2.w + w3 * r3.w;
    *(float4*)(context + (size_t)b * PD + off) = o;
  }
}

// ---------------------------------------------------------------------------
extern "C" void kernel_launch(void* const* d_in, const int* in_sizes, int n_in,
                              void* d_out, int out_size, void* d_ws,
                              size_t ws_size, hipStream_t stream) {
  const float* hidden = (const float*)d_in[0];
  const float* feat   = (const float*)d_in[1];
  const int*   isl    = (const int*)d_in[2];
  const float* Wf     = (const float*)d_in[3];
  const float* bf     = (const float*)d_in[4];
  const float* W1     = (const float*)d_in[5];
  const float* b1     = (const float*)d_in[6];
  const float* W2     = (const float*)d_in[7];
  const float* b2     = (const float*)d_in[8];
  const float* proto  = (const float*)d_in[9];

  float* out = (float*)d_out;
  float* weights = out;                     // [B,K]
  float* logits  = out + (size_t)BB * KK;   // [B,K]
  float* context = out + (size_t)2 * BB * KK;  // [B,PD]

  float* ws = (float*)d_ws;
  float* part   = ws;                                   // SPLIT*B*NF
  float* pooled = part + (size_t)SPLIT * BB * NF;       // B*IN_DIM
  float* hbuf   = pooled + (size_t)BB * IN_DIM;         // B*DH

  feat_partial_kernel<<<dim3(BB, SPLIT), 256, 0, stream>>>(feat, isl, part);
  pooled_kernel<<<BB, 256, 0, stream>>>(hidden, isl, part, Wf, bf, pooled);
  gemm_gelu_kernel<<<dim3(DH / 32, BB / 32), 256, 0, stream>>>(pooled, W1, b1, hbuf);
  head_kernel<<<BB, 64, 0, stream>>>(hbuf, W2, b2, proto, weights, logits, context);
}

// Round 2
// 99.106 us; speedup vs baseline: 1.0770x; 1.0770x over previous
//
#include <hip/hip_runtime.h>
#include <math.h>

#define BB 512      // batch
#define TT 512      // seq len
#define DD 1024     // d_model
#define NF 256      // n_features
#define DE 256      // d_feat_emb
#define DH 512      // d_hidden
#define KK 64       // proto_num
#define PD 1024     // proto_dim
#define IN_DIM (DD + DE)   // 1280
#define SPLIT 4
#define G1_BLOCKS 256      // (DH/32)*(BB/32) = 16*16

__device__ __forceinline__ float gelu_exact(float x) {
  return 0.5f * x * (1.0f + erff(x * 0.70710678118654752440f));
}

// ---------------------------------------------------------------------------
// Kernel 1 (fused, role-split by blockIdx.x):
//  role A (blocks 0..255):    G1 = gather(hidden)[B,1024] @ W1[0:1024,:] + b1
//  role B (blocks 256..2303): part[q][b][f] = partial masked sums of feat
// Roles are independent; memory-bound feat blocks overlap compute-bound GEMM.
// ---------------------------------------------------------------------------
__global__ __launch_bounds__(256) void fused_feat_g1_kernel(
    const float* __restrict__ hidden, const float* __restrict__ feat,
    const int* __restrict__ isl, const float* __restrict__ W1,
    const float* __restrict__ b1, float* __restrict__ part,
    float* __restrict__ G1) {
  __shared__ float As[32][36];
  __shared__ float Bs[32][36];
  __shared__ float red[4][NF];

  int tid = threadIdx.x;

  if (blockIdx.x < G1_BLOCKS) {
    // ----- GEMM role: 32x32 tile, 2x2 per thread, K = 1024 -----
    int bid = blockIdx.x;
    int bx = bid & 15;   // j tile
    int by = bid >> 4;   // b tile
    int tx = tid & 15;
    int ty = tid >> 4;
    int lr = tid >> 3;        // 0..31
    int lc = (tid & 7) * 4;   // 0,4,..,28

    int brow = by * 32 + lr;
    int len = isl[brow];
    len = len < 1 ? 1 : (len > TT ? TT : len);
    const float* Arow = hidden + ((size_t)brow * TT + (len - 1)) * DD;
    const float* Bb = W1 + bx * 32;

    float acc00 = 0.f, acc01 = 0.f, acc10 = 0.f, acc11 = 0.f;
    for (int k0 = 0; k0 < DD; k0 += 32) {
      float4 av = *(const float4*)(Arow + k0 + lc);
      float4 bv = *(const float4*)(Bb + (size_t)(k0 + lr) * DH + lc);
      As[lc + 0][lr] = av.x;
      As[lc + 1][lr] = av.y;
      As[lc + 2][lr] = av.z;
      As[lc + 3][lr] = av.w;
      *(float4*)&Bs[lr][lc] = bv;
      __syncthreads();
#pragma unroll
      for (int kk = 0; kk < 32; ++kk) {
        float2 a = *(float2*)&As[kk][ty * 2];
        float2 bq = *(float2*)&Bs[kk][tx * 2];
        acc00 += a.x * bq.x;
        acc01 += a.x * bq.y;
        acc10 += a.y * bq.x;
        acc11 += a.y * bq.y;
      }
      __syncthreads();
    }
    int row = by * 32 + ty * 2;
    int col = bx * 32 + tx * 2;
    float bi0 = b1[col], bi1 = b1[col + 1];
    G1[(size_t)row * DH + col]           = acc00 + bi0;
    G1[(size_t)row * DH + col + 1]       = acc01 + bi1;
    G1[(size_t)(row + 1) * DH + col]     = acc10 + bi0;
    G1[(size_t)(row + 1) * DH + col + 1] = acc11 + bi1;
  } else {
    // ----- feat partial-sum role -----
    int fid = blockIdx.x - G1_BLOCKS;
    int b = fid & (BB - 1);
    int q = fid >> 9;
    int len = isl[b];
    len = len < 1 ? 1 : (len > TT ? TT : len);
    int lo = (q * len) / SPLIT;
    int hi = ((q + 1) * len) / SPLIT;
    int wave = tid >> 6;
    int lane = tid & 63;
    const float* fb = feat + (size_t)b * TT * NF;

    float4 a0 = {0.f, 0.f, 0.f, 0.f}, a1 = a0, a2 = a0, a3 = a0;
    int t = lo + wave;
    for (; t + 12 < hi; t += 16) {
      float4 v0 = *(const float4*)(fb + (size_t)t * NF + lane * 4);
      float4 v1 = *(const float4*)(fb + (size_t)(t + 4) * NF + lane * 4);
      float4 v2 = *(const float4*)(fb + (size_t)(t + 8) * NF + lane * 4);
      float4 v3 = *(const float4*)(fb + (size_t)(t + 12) * NF + lane * 4);
      a0.x += v0.x; a0.y += v0.y; a0.z += v0.z; a0.w += v0.w;
      a1.x += v1.x; a1.y += v1.y; a1.z += v1.z; a1.w += v1.w;
      a2.x += v2.x; a2.y += v2.y; a2.z += v2.z; a2.w += v2.w;
      a3.x += v3.x; a3.y += v3.y; a3.z += v3.z; a3.w += v3.w;
    }
    for (; t < hi; t += 4) {
      float4 v0 = *(const float4*)(fb + (size_t)t * NF + lane * 4);
      a0.x += v0.x; a0.y += v0.y; a0.z += v0.z; a0.w += v0.w;
    }
    float4 acc;
    acc.x = a0.x + a1.x + a2.x + a3.x;
    acc.y = a0.y + a1.y + a2.y + a3.y;
    acc.z = a0.z + a1.z + a2.z + a3.z;
    acc.w = a0.w + a1.w + a2.w + a3.w;

    *(float4*)&red[wave][lane * 4] = acc;
    __syncthreads();
    int f = tid;
    float s = red[0][f] + red[1][f] + red[2][f] + red[3][f];
    part[((size_t)q * BB + b) * NF + f] = s;
  }
}

// ---------------------------------------------------------------------------
// Kernel 2: f_emb = (reduce(part)/len) @ Wf + bf. 64 blocks x 8 batches.
// ---------------------------------------------------------------------------
__global__ __launch_bounds__(256) void femb_kernel(
    const int* __restrict__ isl, const float* __restrict__ part,
    const float* __restrict__ Wf, const float* __restrict__ bf,
    float* __restrict__ femb) {
  __shared__ float sm[8][NF];
  int tid = threadIdx.x;
  int b0 = blockIdx.x * 8;

#pragma unroll
  for (int bb = 0; bb < 8; ++bb) {
    int b = b0 + bb;
    int len = isl[b];
    len = len < 1 ? 1 : (len > TT ? TT : len);
    float s = part[((size_t)0 * BB + b) * NF + tid] +
              part[((size_t)1 * BB + b) * NF + tid] +
              part[((size_t)2 * BB + b) * NF + tid] +
              part[((size_t)3 * BB + b) * NF + tid];
    sm[bb][tid] = s / (float)len;
  }
  __syncthreads();

  float acc0 = bf[tid], acc1 = acc0, acc2 = acc0, acc3 = acc0;
  float acc4 = acc0, acc5 = acc0, acc6 = acc0, acc7 = acc0;
  acc1 = acc2 = acc3 = acc4 = acc5 = acc6 = acc7 = 0.f;
#pragma unroll 4
  for (int i = 0; i < NF; ++i) {
    float w = Wf[(size_t)i * DE + tid];
    acc0 += sm[0][i] * w;
    acc1 += sm[1][i] * w;
    acc2 += sm[2][i] * w;
    acc3 += sm[3][i] * w;
    acc4 += sm[4][i] * w;
    acc5 += sm[5][i] * w;
    acc6 += sm[6][i] * w;
    acc7 += sm[7][i] * w;
  }
  float base = bf[tid];
  femb[(size_t)(b0 + 0) * DE + tid] = acc0;           // acc0 already has bf
  femb[(size_t)(b0 + 1) * DE + tid] = acc1 + base;
  femb[(size_t)(b0 + 2) * DE + tid] = acc2 + base;
  femb[(size_t)(b0 + 3) * DE + tid] = acc3 + base;
  femb[(size_t)(b0 + 4) * DE + tid] = acc4 + base;
  femb[(size_t)(b0 + 5) * DE + tid] = acc5 + base;
  femb[(size_t)(b0 + 6) * DE + tid] = acc6 + base;
  femb[(size_t)(b0 + 7) * DE + tid] = acc7 + base;
}

// ---------------------------------------------------------------------------
// Kernel 3: h = gelu(G1 + femb @ W1[1024:1280,:]). 32x32 tile, K = 256.
// ---------------------------------------------------------------------------
__global__ __launch_bounds__(256) void g2_gelu_kernel(
    const float* __restrict__ femb, const float* __restrict__ W1,
    const float* __restrict__ G1, float* __restrict__ h) {
  __shared__ float As[32][36];
  __shared__ float Bs[32][36];
  int bx = blockIdx.x;
  int by = blockIdx.y;
  int tid = threadIdx.x;
  int tx = tid & 15;
  int ty = tid >> 4;
  int lr = tid >> 3;
  int lc = (tid & 7) * 4;

  const float* Ab = femb + (size_t)(by * 32) * DE;
  const float* Bb = W1 + (size_t)DD * DH + bx * 32;
  float acc00 = 0.f, acc01 = 0.f, acc10 = 0.f, acc11 = 0.f;

  for (int k0 = 0; k0 < DE; k0 += 32) {
    float4 av = *(const float4*)(Ab + (size_t)lr * DE + k0 + lc);
    float4 bv = *(const float4*)(Bb + (size_t)(k0 + lr) * DH + lc);
    As[lc + 0][lr] = av.x;
    As[lc + 1][lr] = av.y;
    As[lc + 2][lr] = av.z;
    As[lc + 3][lr] = av.w;
    *(float4*)&Bs[lr][lc] = bv;
    __syncthreads();
#pragma unroll
    for (int kk = 0; kk < 32; ++kk) {
      float2 a = *(float2*)&As[kk][ty * 2];
      float2 bq = *(float2*)&Bs[kk][tx * 2];
      acc00 += a.x * bq.x;
      acc01 += a.x * bq.y;
      acc10 += a.y * bq.x;
      acc11 += a.y * bq.y;
    }
    __syncthreads();
  }
  int row = by * 32 + ty * 2;
  int col = bx * 32 + tx * 2;
  float2 g0 = *(const float2*)(G1 + (size_t)row * DH + col);
  float2 g1 = *(const float2*)(G1 + (size_t)(row + 1) * DH + col);
  h[(size_t)row * DH + col]           = gelu_exact(acc00 + g0.x);
  h[(size_t)row * DH + col + 1]       = gelu_exact(acc01 + g0.y);
  h[(size_t)(row + 1) * DH + col]     = gelu_exact(acc10 + g1.x);
  h[(size_t)(row + 1) * DH + col + 1] = gelu_exact(acc11 + g1.y);
}

// ---------------------------------------------------------------------------
// Kernel 4: logits, top-4 softmax gating, context. One wave per batch.
// ---------------------------------------------------------------------------
__global__ __launch_bounds__(64) void head_kernel(
    const float* __restrict__ h, const float* __restrict__ W2,
    const float* __restrict__ b2, const float* __restrict__ proto,
    float* __restrict__ weights, float* __restrict__ logits_out,
    float* __restrict__ context) {
  int b = blockIdx.x;
  int lane = threadIdx.x;

  __shared__ float hs[DH];
  {
    float4 v0 = *(const float4*)(h + (size_t)b * DH + lane * 4);
    float4 v1 = *(const float4*)(h + (size_t)b * DH + 256 + lane * 4);
    *(float4*)&hs[lane * 4] = v0;
    *(float4*)&hs[256 + lane * 4] = v1;
  }
  __syncthreads();

  float acc = b2[lane];
#pragma unroll 8
  for (int i = 0; i < DH; ++i) acc += hs[i] * W2[i * KK + lane];
  logits_out[(size_t)b * KK + lane] = acc;  // TEMP == 1.0

  // top-4 (desc, ties -> lower index, matching jax.lax.top_k)
  float cur = acc;
  float tv[4];
  int ti[4];
#pragma unroll
  for (int r = 0; r < 4; ++r) {
    float mv = cur;
    int mi = lane;
#pragma unroll
    for (int off = 32; off; off >>= 1) {
      float ov = __shfl_xor(mv, off);
      int oi = __shfl_xor(mi, off);
      if (ov > mv || (ov == mv && oi < mi)) { mv = ov; mi = oi; }
    }
    tv[r] = mv;
    ti[r] = mi;
    if (lane == mi) cur = -INFINITY;
  }
  float m = tv[0];
  float e0 = expf(tv[0] - m), e1 = expf(tv[1] - m);
  float e2 = expf(tv[2] - m), e3 = expf(tv[3] - m);
  float inv = 1.0f / (e0 + e1 + e2 + e3);
  float w0 = e0 * inv, w1 = e1 * inv, w2 = e2 * inv, w3 = e3 * inv;

  float wt = 0.f;
  if (lane == ti[0]) wt = w0;
  else if (lane == ti[1]) wt = w1;
  else if (lane == ti[2]) wt = w2;
  else if (lane == ti[3]) wt = w3;
  weights[(size_t)b * KK + lane] = wt;

  const float* p0 = proto + (size_t)ti[0] * PD;
  const float* p1 = proto + (size_t)ti[1] * PD;
  const float* p2 = proto + (size_t)ti[2] * PD;
  const float* p3 = proto + (size_t)ti[3] * PD;
#pragma unroll
  for (int q2 = 0; q2 < 4; ++q2) {
    int off = q2 * 256 + lane * 4;
    float4 r0 = *(const float4*)(p0 + off);
    float4 r1 = *(const float4*)(p1 + off);
    float4 r2 = *(const float4*)(p2 + off);
    float4 r3 = *(const float4*)(p3 + off);
    float4 o;
    o.x = w0 * r0.x + w1 * r1.x + w2 * r2.x + w3 * r3.x;
    o.y = w0 * r0.y + w1 * r1.y + w2 * r2.y + w3 * r3.y;
    o.z = w0 * r0.z + w1 * r1.z + w2 * r2.z + w3 * r3.z;
    o.w = w0 * r0.w + w1 * r1.w + w2 * r2.w + w3 * r3.w;
    *(float4*)(context + (size_t)b * PD + off) = o;
  }
}

// ---------------------------------------------------------------------------
extern "C" void kernel_launch(void* const* d_in, const int* in_sizes, int n_in,
                              void* d_out, int out_size, void* d_ws,
                              size_t ws_size, hipStream_t stream) {
  const float* hidden = (const float*)d_in[0];
  const float* feat   = (const float*)d_in[1];
  const int*   isl    = (const int*)d_in[2];
  const float* Wf     = (const float*)d_in[3];
  const float* bf     = (const float*)d_in[4];
  const float* W1     = (const float*)d_in[5];
  const float* b1     = (const float*)d_in[6];
  const float* W2     = (const float*)d_in[7];
  const float* b2     = (const float*)d_in[8];
  const float* proto  = (const float*)d_in[9];

  float* out = (float*)d_out;
  float* weights = out;                        // [B,K]
  float* logits  = out + (size_t)BB * KK;      // [B,K]
  float* context = out + (size_t)2 * BB * KK;  // [B,PD]

  float* ws = (float*)d_ws;
  float* part = ws;                                  // SPLIT*B*NF
  float* femb = part + (size_t)SPLIT * BB * NF;      // B*DE
  float* G1   = femb + (size_t)BB * DE;              // B*DH
  float* hbuf = G1 + (size_t)BB * DH;                // B*DH

  fused_feat_g1_kernel<<<G1_BLOCKS + BB * SPLIT, 256, 0, stream>>>(
      hidden, feat, isl, W1, b1, part, G1);
  femb_kernel<<<BB / 8, 256, 0, stream>>>(isl, part, Wf, bf, femb);
  g2_gelu_kernel<<<dim3(DH / 32, BB / 32), 256, 0, stream>>>(femb, W1, G1, hbuf);
  head_kernel<<<BB, 64, 0, stream>>>(hbuf, W2, b2, proto, weights, logits, context);
}

// Round 3
// 80.514 us; speedup vs baseline: 1.3257x; 1.2309x over previous
//
#include <hip/hip_runtime.h>
#include <math.h>

#define BB 512      // batch
#define TT 512      // seq len
#define DD 1024     // d_model
#define NF 256      // n_features
#define DE 256      // d_feat_emb
#define DH 512      // d_hidden
#define KK 64       // proto_num
#define PD 1024     // proto_dim
#define IN_DIM (DD + DE)   // 1280
#define SPLIT 4
#define G1_BLOCKS 256      // (DH/32)*(BB/32)

__device__ __forceinline__ float gelu_exact(float x) {
  return 0.5f * x * (1.0f + erff(x * 0.70710678118654752440f));
}

// ---------------------------------------------------------------------------
// Kernel A (role-split):
//  blocks 0..255:    G1 = gather(hidden)[B,1024] @ W1[0:1024,:] + b1
//  blocks 256..2303: part[q][b][f] = partial masked sums of feat
// ---------------------------------------------------------------------------
__global__ __launch_bounds__(256) void fused_feat_g1_kernel(
    const float* __restrict__ hidden, const float* __restrict__ feat,
    const int* __restrict__ isl, const float* __restrict__ W1,
    const float* __restrict__ b1, float* __restrict__ part,
    float* __restrict__ G1) {
  __shared__ float As[32][36];
  __shared__ float Bs[32][36];
  __shared__ float red[4][NF];

  int tid = threadIdx.x;

  if (blockIdx.x < G1_BLOCKS) {
    int bid = blockIdx.x;
    int bx = bid & 15;   // j tile
    int by = bid >> 4;   // b tile
    int tx = tid & 15;
    int ty = tid >> 4;
    int lr = tid >> 3;
    int lc = (tid & 7) * 4;

    int brow = by * 32 + lr;
    int len = isl[brow];
    len = len < 1 ? 1 : (len > TT ? TT : len);
    const float* Arow = hidden + ((size_t)brow * TT + (len - 1)) * DD;
    const float* Bb = W1 + bx * 32;

    float acc00 = 0.f, acc01 = 0.f, acc10 = 0.f, acc11 = 0.f;
    for (int k0 = 0; k0 < DD; k0 += 32) {
      float4 av = *(const float4*)(Arow + k0 + lc);
      float4 bv = *(const float4*)(Bb + (size_t)(k0 + lr) * DH + lc);
      As[lc + 0][lr] = av.x;
      As[lc + 1][lr] = av.y;
      As[lc + 2][lr] = av.z;
      As[lc + 3][lr] = av.w;
      *(float4*)&Bs[lr][lc] = bv;
      __syncthreads();
#pragma unroll
      for (int kk = 0; kk < 32; ++kk) {
        float2 a = *(float2*)&As[kk][ty * 2];
        float2 bq = *(float2*)&Bs[kk][tx * 2];
        acc00 += a.x * bq.x;
        acc01 += a.x * bq.y;
        acc10 += a.y * bq.x;
        acc11 += a.y * bq.y;
      }
      __syncthreads();
    }
    int row = by * 32 + ty * 2;
    int col = bx * 32 + tx * 2;
    float bi0 = b1[col], bi1 = b1[col + 1];
    G1[(size_t)row * DH + col]           = acc00 + bi0;
    G1[(size_t)row * DH + col + 1]       = acc01 + bi1;
    G1[(size_t)(row + 1) * DH + col]     = acc10 + bi0;
    G1[(size_t)(row + 1) * DH + col + 1] = acc11 + bi1;
  } else {
    int fid = blockIdx.x - G1_BLOCKS;
    int b = fid & (BB - 1);
    int q = fid >> 9;
    int len = isl[b];
    len = len < 1 ? 1 : (len > TT ? TT : len);
    int lo = (q * len) / SPLIT;
    int hi = ((q + 1) * len) / SPLIT;
    int wave = tid >> 6;
    int lane = tid & 63;
    const float* fb = feat + (size_t)b * TT * NF;

    float4 a0 = {0.f, 0.f, 0.f, 0.f}, a1 = a0, a2 = a0, a3 = a0;
    int t = lo + wave;
    for (; t + 12 < hi; t += 16) {
      float4 v0 = *(const float4*)(fb + (size_t)t * NF + lane * 4);
      float4 v1 = *(const float4*)(fb + (size_t)(t + 4) * NF + lane * 4);
      float4 v2 = *(const float4*)(fb + (size_t)(t + 8) * NF + lane * 4);
      float4 v3 = *(const float4*)(fb + (size_t)(t + 12) * NF + lane * 4);
      a0.x += v0.x; a0.y += v0.y; a0.z += v0.z; a0.w += v0.w;
      a1.x += v1.x; a1.y += v1.y; a1.z += v1.z; a1.w += v1.w;
      a2.x += v2.x; a2.y += v2.y; a2.z += v2.z; a2.w += v2.w;
      a3.x += v3.x; a3.y += v3.y; a3.z += v3.z; a3.w += v3.w;
    }
    for (; t < hi; t += 4) {
      float4 v0 = *(const float4*)(fb + (size_t)t * NF + lane * 4);
      a0.x += v0.x; a0.y += v0.y; a0.z += v0.z; a0.w += v0.w;
    }
    float4 acc;
    acc.x = a0.x + a1.x + a2.x + a3.x;
    acc.y = a0.y + a1.y + a2.y + a3.y;
    acc.z = a0.z + a1.z + a2.z + a3.z;
    acc.w = a0.w + a1.w + a2.w + a3.w;

    *(float4*)&red[wave][lane * 4] = acc;
    __syncthreads();
    int f = tid;
    float s = red[0][f] + red[1][f] + red[2][f] + red[3][f];
    part[((size_t)q * BB + b) * NF + f] = s;
  }
}

// ---------------------------------------------------------------------------
// Kernel B: fully-fused stage 2. 256 blocks x 256 thr, 2 batches per block.
//   fmean -> femb -> h = gelu(G1 + femb@W1b) -> logits -> top4 -> context
// Weights are L2-resident; each weight load amortized over 2 batches.
// ---------------------------------------------------------------------------
__global__ __launch_bounds__(256) void stage2_kernel(
    const int* __restrict__ isl, const float* __restrict__ part,
    const float* __restrict__ Wf, const float* __restrict__ bf,
    const float* __restrict__ W1, const float* __restrict__ G1,
    const float* __restrict__ W2, const float* __restrict__ b2,
    const float* __restrict__ proto, float* __restrict__ weights,
    float* __restrict__ logits_out, float* __restrict__ context) {
  int tid = threadIdx.x;
  int b0 = blockIdx.x * 2;

  __shared__ float fm[2][NF];
  __shared__ float fe[2][NF];
  __shared__ float hs[2][DH];
  __shared__ float lred[2][4][KK];
  __shared__ float gw[2][4];
  __shared__ int   gi[2][4];

  // ---- fmean = reduce(part)/len ----
#pragma unroll
  for (int bb = 0; bb < 2; ++bb) {
    int b = b0 + bb;
    int len = isl[b];
    len = len < 1 ? 1 : (len > TT ? TT : len);
    float s = part[((size_t)0 * BB + b) * NF + tid] +
              part[((size_t)1 * BB + b) * NF + tid] +
              part[((size_t)2 * BB + b) * NF + tid] +
              part[((size_t)3 * BB + b) * NF + tid];
    fm[bb][tid] = s / (float)len;
  }
  __syncthreads();

  // ---- femb = fmean @ Wf + bf ----
  {
    float a0 = 0.f, a1 = 0.f;
#pragma unroll 8
    for (int i = 0; i < NF; ++i) {
      float w = Wf[(size_t)i * DE + tid];
      a0 += fm[0][i] * w;
      a1 += fm[1][i] * w;
    }
    float base = bf[tid];
    fe[0][tid] = a0 + base;
    fe[1][tid] = a1 + base;
  }
  __syncthreads();

  // ---- h = gelu(G1 + femb @ W1[1024:,:]) ; cols tid, tid+256 ----
  {
    const float* W1b = W1 + (size_t)DD * DH;
    float h00 = 0.f, h01 = 0.f, h10 = 0.f, h11 = 0.f;
#pragma unroll 8
    for (int i = 0; i < DE; ++i) {
      float w0 = W1b[(size_t)i * DH + tid];
      float w1 = W1b[(size_t)i * DH + tid + 256];
      float f0 = fe[0][i];
      float f1 = fe[1][i];
      h00 += f0 * w0;
      h01 += f0 * w1;
      h10 += f1 * w0;
      h11 += f1 * w1;
    }
    hs[0][tid]       = gelu_exact(h00 + G1[(size_t)b0 * DH + tid]);
    hs[0][tid + 256] = gelu_exact(h01 + G1[(size_t)b0 * DH + tid + 256]);
    hs[1][tid]       = gelu_exact(h10 + G1[(size_t)(b0 + 1) * DH + tid]);
    hs[1][tid + 256] = gelu_exact(h11 + G1[(size_t)(b0 + 1) * DH + tid + 256]);
  }
  __syncthreads();

  // ---- logits partials: 4 segments of 128 over DH ----
  {
    int j = tid & 63;
    int seg = tid >> 6;
    float l0 = 0.f, l1 = 0.f;
    int i0 = seg * 128;
#pragma unroll 8
    for (int i = i0; i < i0 + 128; ++i) {
      float w = W2[(size_t)i * KK + j];
      l0 += hs[0][i] * w;
      l1 += hs[1][i] * w;
    }
    lred[0][seg][j] = l0;
    lred[1][seg][j] = l1;
  }
  __syncthreads();

  // ---- finalize logits + top-4 softmax gating (wave 0 -> b0, wave 1 -> b1)
  if (tid < 128) {
    int bb = tid >> 6;
    int lane = tid & 63;
    float lg = lred[bb][0][lane] + lred[bb][1][lane] + lred[bb][2][lane] +
               lred[bb][3][lane] + b2[lane];
    logits_out[(size_t)(b0 + bb) * KK + lane] = lg;  // TEMP == 1.0

    float cur = lg;
    float tv[4];
    int ti[4];
#pragma unroll
    for (int r = 0; r < 4; ++r) {
      float mv = cur;
      int mi = lane;
#pragma unroll
      for (int off = 32; off; off >>= 1) {
        float ov = __shfl_xor(mv, off);
        int oi = __shfl_xor(mi, off);
        if (ov > mv || (ov == mv && oi < mi)) { mv = ov; mi = oi; }
      }
      tv[r] = mv;
      ti[r] = mi;
      if (lane == mi) cur = -INFINITY;
    }
    float m = tv[0];
    float e0 = expf(tv[0] - m), e1 = expf(tv[1] - m);
    float e2 = expf(tv[2] - m), e3 = expf(tv[3] - m);
    float inv = 1.0f / (e0 + e1 + e2 + e3);
    float w0 = e0 * inv, w1 = e1 * inv, w2 = e2 * inv, w3 = e3 * inv;

    float wt = 0.f;
    if (lane == ti[0]) wt = w0;
    else if (lane == ti[1]) wt = w1;
    else if (lane == ti[2]) wt = w2;
    else if (lane == ti[3]) wt = w3;
    weights[(size_t)(b0 + bb) * KK + lane] = wt;

    if (lane == 0) {
      gw[bb][0] = w0; gw[bb][1] = w1; gw[bb][2] = w2; gw[bb][3] = w3;
      gi[bb][0] = ti[0]; gi[bb][1] = ti[1]; gi[bb][2] = ti[2]; gi[bb][3] = ti[3];
    }
  }
  __syncthreads();

  // ---- context = weights @ proto (4 sparse rows per batch) ----
#pragma unroll
  for (int bb = 0; bb < 2; ++bb) {
    float w0 = gw[bb][0], w1 = gw[bb][1], w2 = gw[bb][2], w3 = gw[bb][3];
    const float* p0 = proto + (size_t)gi[bb][0] * PD;
    const float* p1 = proto + (size_t)gi[bb][1] * PD;
    const float* p2 = proto + (size_t)gi[bb][2] * PD;
    const float* p3 = proto + (size_t)gi[bb][3] * PD;
    int off = tid * 4;
    float4 r0 = *(const float4*)(p0 + off);
    float4 r1 = *(const float4*)(p1 + off);
    float4 r2 = *(const float4*)(p2 + off);
    float4 r3 = *(const float4*)(p3 + off);
    float4 o;
    o.x = w0 * r0.x + w1 * r1.x + w2 * r2.x + w3 * r3.x;
    o.y = w0 * r0.y + w1 * r1.y + w2 * r2.y + w3 * r3.y;
    o.z = w0 * r0.z + w1 * r1.z + w2 * r2.z + w3 * r3.z;
    o.w = w0 * r0.w + w1 * r1.w + w2 * r2.w + w3 * r3.w;
    *(float4*)(context + (size_t)(b0 + bb) * PD + off) = o;
  }
}

// ---------------------------------------------------------------------------
extern "C" void kernel_launch(void* const* d_in, const int* in_sizes, int n_in,
                              void* d_out, int out_size, void* d_ws,
                              size_t ws_size, hipStream_t stream) {
  const float* hidden = (const float*)d_in[0];
  const float* feat   = (const float*)d_in[1];
  const int*   isl    = (const int*)d_in[2];
  const float* Wf     = (const float*)d_in[3];
  const float* bf     = (const float*)d_in[4];
  const float* W1     = (const float*)d_in[5];
  const float* b1     = (const float*)d_in[6];
  const float* W2     = (const float*)d_in[7];
  const float* b2     = (const float*)d_in[8];
  const float* proto  = (const float*)d_in[9];

  float* out = (float*)d_out;
  float* weights = out;                        // [B,K]
  float* logits  = out + (size_t)BB * KK;      // [B,K]
  float* context = out + (size_t)2 * BB * KK;  // [B,PD]

  float* ws = (float*)d_ws;
  float* part = ws;                                  // SPLIT*B*NF
  float* G1   = part + (size_t)SPLIT * BB * NF;      // B*DH

  fused_feat_g1_kernel<<<G1_BLOCKS + BB * SPLIT, 256, 0, stream>>>(
      hidden, feat, isl, W1, b1, part, G1);
  stage2_kernel<<<BB / 2, 256, 0, stream>>>(isl, part, Wf, bf, W1, G1, W2, b2,
                                            proto, weights, logits, context);
}

// Round 4
// 71.235 us; speedup vs baseline: 1.4984x; 1.1303x over previous
//
#include <hip/hip_runtime.h>
#include <math.h>

#define BB 512      // batch
#define TT 512      // seq len
#define DD 1024     // d_model
#define NF 256      // n_features
#define DE 256      // d_feat_emb
#define DH 512      // d_hidden
#define KK 64       // proto_num
#define PD 1024     // proto_dim
#define SPLIT 4
#define KSPLIT 16          // G1 K-chunks of 64
#define GB 256             // G1 blocks: 16 batch-tiles x 16 k-chunks

__device__ __forceinline__ float gelu_exact(float x) {
  return 0.5f * x * (1.0f + erff(x * 0.70710678118654752440f));
}

// ---------------------------------------------------------------------------
// Kernel A (role-split):
//  blocks 0..255:    G1p[ks] = gather(hidden)[32 batches] @ W1[ks*64:+64, :]
//                    (8x8 reg tile, A via LDS broadcast, B streamed from L2)
//  blocks 256..2303: part[q][b][f] = partial masked sums of feat (HBM-bound)
// GEMM is VALU-bound ~3.4us/CU and hides under the feat HBM reads.
// ---------------------------------------------------------------------------
__global__ __launch_bounds__(256) void kernelA(
    const float* __restrict__ hidden, const float* __restrict__ feat,
    const int* __restrict__ isl, const float* __restrict__ W1,
    float* __restrict__ part, float* __restrict__ G1p) {
  __shared__ float As[64][36];   // As[k][batch_row], padded for f4 alignment
  __shared__ float red[4][NF];

  int tid = threadIdx.x;

  if (blockIdx.x < GB) {
    // ----- G1 partial GEMM role -----
    int bid = blockIdx.x;
    int by = bid >> 4;   // batch tile 0..15 (32 batches each)
    int ks = bid & 15;   // k chunk 0..15 (64 ks each)
    int k0 = ks * 64;

    // stage A chunk transposed: As[k][row] = hidden[b, len-1, k0+k]
    {
      int row = tid >> 3;       // 0..31
      int kq = tid & 7;         // 0..7 -> 8 k's
      int b = by * 32 + row;
      int len = isl[b];
      len = len < 1 ? 1 : (len > TT ? TT : len);
      const float* ap = hidden + ((size_t)b * TT + (len - 1)) * DD + k0 + kq * 8;
      float4 a0 = *(const float4*)ap;
      float4 a1 = *(const float4*)(ap + 4);
      As[kq * 8 + 0][row] = a0.x;
      As[kq * 8 + 1][row] = a0.y;
      As[kq * 8 + 2][row] = a0.z;
      As[kq * 8 + 3][row] = a0.w;
      As[kq * 8 + 4][row] = a1.x;
      As[kq * 8 + 5][row] = a1.y;
      As[kq * 8 + 6][row] = a1.z;
      As[kq * 8 + 7][row] = a1.w;
    }
    __syncthreads();

    int cg = tid & 63;   // col group: cols cg*8..+7 (lane id -> coalesced B)
    int bg = tid >> 6;   // batch group: rows bg*8..+7 (uniform per wave)
    const float* Bp = W1 + (size_t)k0 * DH + cg * 8;

    float acc[8][8];
#pragma unroll
    for (int i = 0; i < 8; ++i)
#pragma unroll
      for (int j = 0; j < 8; ++j) acc[i][j] = 0.f;

#pragma unroll 4
    for (int k = 0; k < 64; ++k) {
      float4 w0 = *(const float4*)(Bp + (size_t)k * DH);
      float4 w1 = *(const float4*)(Bp + (size_t)k * DH + 4);
      float4 a0 = *(const float4*)&As[k][bg * 8];       // wave-broadcast
      float4 a1 = *(const float4*)&As[k][bg * 8 + 4];
      float aa[8] = {a0.x, a0.y, a0.z, a0.w, a1.x, a1.y, a1.z, a1.w};
      float ww[8] = {w0.x, w0.y, w0.z, w0.w, w1.x, w1.y, w1.z, w1.w};
#pragma unroll
      for (int i = 0; i < 8; ++i)
#pragma unroll
        for (int j = 0; j < 8; ++j) acc[i][j] += aa[i] * ww[j];
    }

#pragma unroll
    for (int i = 0; i < 8; ++i) {
      int brow = by * 32 + bg * 8 + i;
      float* dst = G1p + ((size_t)ks * BB + brow) * DH + cg * 8;
      float4 o0 = {acc[i][0], acc[i][1], acc[i][2], acc[i][3]};
      float4 o1 = {acc[i][4], acc[i][5], acc[i][6], acc[i][7]};
      *(float4*)dst = o0;
      *(float4*)(dst + 4) = o1;
    }
  } else {
    // ----- feat partial-sum role -----
    int fid = blockIdx.x - GB;
    int b = fid & (BB - 1);
    int q = fid >> 9;
    int len = isl[b];
    len = len < 1 ? 1 : (len > TT ? TT : len);
    int lo = (q * len) / SPLIT;
    int hi = ((q + 1) * len) / SPLIT;
    int wave = tid >> 6;
    int lane = tid & 63;
    const float* fb = feat + (size_t)b * TT * NF;

    float4 a0 = {0.f, 0.f, 0.f, 0.f}, a1 = a0, a2 = a0, a3 = a0;
    int t = lo + wave;
    for (; t + 12 < hi; t += 16) {
      float4 v0 = *(const float4*)(fb + (size_t)t * NF + lane * 4);
      float4 v1 = *(const float4*)(fb + (size_t)(t + 4) * NF + lane * 4);
      float4 v2 = *(const float4*)(fb + (size_t)(t + 8) * NF + lane * 4);
      float4 v3 = *(const float4*)(fb + (size_t)(t + 12) * NF + lane * 4);
      a0.x += v0.x; a0.y += v0.y; a0.z += v0.z; a0.w += v0.w;
      a1.x += v1.x; a1.y += v1.y; a1.z += v1.z; a1.w += v1.w;
      a2.x += v2.x; a2.y += v2.y; a2.z += v2.z; a2.w += v2.w;
      a3.x += v3.x; a3.y += v3.y; a3.z += v3.z; a3.w += v3.w;
    }
    for (; t < hi; t += 4) {
      float4 v0 = *(const float4*)(fb + (size_t)t * NF + lane * 4);
      a0.x += v0.x; a0.y += v0.y; a0.z += v0.z; a0.w += v0.w;
    }
    float4 acc;
    acc.x = a0.x + a1.x + a2.x + a3.x;
    acc.y = a0.y + a1.y + a2.y + a3.y;
    acc.z = a0.z + a1.z + a2.z + a3.z;
    acc.w = a0.w + a1.w + a2.w + a3.w;

    *(float4*)&red[wave][lane * 4] = acc;
    __syncthreads();
    int f = tid;
    float s = red[0][f] + red[1][f] + red[2][f] + red[3][f];
    part[((size_t)q * BB + b) * NF + f] = s;
  }
}

// ---------------------------------------------------------------------------
// Kernel B: fused stage 2. 256 blocks x 256 thr, 2 batches per block.
//   fmean -> femb -> h = gelu(sum_ks G1p + b1 + femb@W1b) -> logits -> top4
//   -> context. Weights + G1p are L2-resident.
// ---------------------------------------------------------------------------
__global__ __launch_bounds__(256) void stage2_kernel(
    const int* __restrict__ isl, const float* __restrict__ part,
    const float* __restrict__ Wf, const float* __restrict__ bf,
    const float* __restrict__ W1, const float* __restrict__ b1,
    const float* __restrict__ G1p, const float* __restrict__ W2,
    const float* __restrict__ b2, const float* __restrict__ proto,
    float* __restrict__ weights, float* __restrict__ logits_out,
    float* __restrict__ context) {
  int tid = threadIdx.x;
  int b0 = blockIdx.x * 2;

  __shared__ float fm[2][NF];
  __shared__ float fe[2][NF];
  __shared__ float hs[2][DH];
  __shared__ float lred[2][4][KK];
  __shared__ float gw[2][4];
  __shared__ int   gi[2][4];

  // ---- fmean = reduce(part)/len ----
#pragma unroll
  for (int bb = 0; bb < 2; ++bb) {
    int b = b0 + bb;
    int len = isl[b];
    len = len < 1 ? 1 : (len > TT ? TT : len);
    float s = part[((size_t)0 * BB + b) * NF + tid] +
              part[((size_t)1 * BB + b) * NF + tid] +
              part[((size_t)2 * BB + b) * NF + tid] +
              part[((size_t)3 * BB + b) * NF + tid];
    fm[bb][tid] = s / (float)len;
  }
  __syncthreads();

  // ---- femb = fmean @ Wf + bf ----
  {
    float a0 = 0.f, a1 = 0.f;
#pragma unroll 8
    for (int i = 0; i < NF; ++i) {
      float w = Wf[(size_t)i * DE + tid];
      a0 += fm[0][i] * w;
      a1 += fm[1][i] * w;
    }
    float base = bf[tid];
    fe[0][tid] = a0 + base;
    fe[1][tid] = a1 + base;
  }
  __syncthreads();

  // ---- h = gelu(G1 + b1 + femb @ W1[1024:,:]) ; cols tid, tid+256 ----
  {
    const float* W1b = W1 + (size_t)DD * DH;
    float h00 = 0.f, h01 = 0.f, h10 = 0.f, h11 = 0.f;
#pragma unroll 8
    for (int i = 0; i < DE; ++i) {
      float w0 = W1b[(size_t)i * DH + tid];
      float w1 = W1b[(size_t)i * DH + tid + 256];
      float f0 = fe[0][i];
      float f1 = fe[1][i];
      h00 += f0 * w0;
      h01 += f0 * w1;
      h10 += f1 * w0;
      h11 += f1 * w1;
    }
    // reduce the 16 K-split partials of G1 (fixed order -> deterministic)
    float g00 = 0.f, g01 = 0.f, g10 = 0.f, g11 = 0.f;
#pragma unroll 4
    for (int ksI = 0; ksI < KSPLIT; ++ksI) {
      const float* gp = G1p + (size_t)ksI * BB * DH;
      g00 += gp[(size_t)b0 * DH + tid];
      g01 += gp[(size_t)b0 * DH + tid + 256];
      g10 += gp[(size_t)(b0 + 1) * DH + tid];
      g11 += gp[(size_t)(b0 + 1) * DH + tid + 256];
    }
    float bb0 = b1[tid], bb1 = b1[tid + 256];
    hs[0][tid]       = gelu_exact(h00 + g00 + bb0);
    hs[0][tid + 256] = gelu_exact(h01 + g01 + bb1);
    hs[1][tid]       = gelu_exact(h10 + g10 + bb0);
    hs[1][tid + 256] = gelu_exact(h11 + g11 + bb1);
  }
  __syncthreads();

  // ---- logits partials: 4 segments of 128 over DH ----
  {
    int j = tid & 63;
    int seg = tid >> 6;
    float l0 = 0.f, l1 = 0.f;
    int i0 = seg * 128;
#pragma unroll 8
    for (int i = i0; i < i0 + 128; ++i) {
      float w = W2[(size_t)i * KK + j];
      l0 += hs[0][i] * w;
      l1 += hs[1][i] * w;
    }
    lred[0][seg][j] = l0;
    lred[1][seg][j] = l1;
  }
  __syncthreads();

  // ---- finalize logits + top-4 softmax gating (wave0 -> b0, wave1 -> b1) --
  if (tid < 128) {
    int bb = tid >> 6;
    int lane = tid & 63;
    float lg = lred[bb][0][lane] + lred[bb][1][lane] + lred[bb][2][lane] +
               lred[bb][3][lane] + b2[lane];
    logits_out[(size_t)(b0 + bb) * KK + lane] = lg;  // TEMP == 1.0

    float cur = lg;
    float tv[4];
    int ti[4];
#pragma unroll
    for (int r = 0; r < 4; ++r) {
      float mv = cur;
      int mi = lane;
#pragma unroll
      for (int off = 32; off; off >>= 1) {
        float ov = __shfl_xor(mv, off);
        int oi = __shfl_xor(mi, off);
        if (ov > mv || (ov == mv && oi < mi)) { mv = ov; mi = oi; }
      }
      tv[r] = mv;
      ti[r] = mi;
      if (lane == mi) cur = -INFINITY;
    }
    float m = tv[0];
    float e0 = expf(tv[0] - m), e1 = expf(tv[1] - m);
    float e2 = expf(tv[2] - m), e3 = expf(tv[3] - m);
    float inv = 1.0f / (e0 + e1 + e2 + e3);
    float w0 = e0 * inv, w1 = e1 * inv, w2 = e2 * inv, w3 = e3 * inv;

    float wt = 0.f;
    if (lane == ti[0]) wt = w0;
    else if (lane == ti[1]) wt = w1;
    else if (lane == ti[2]) wt = w2;
    else if (lane == ti[3]) wt = w3;
    weights[(size_t)(b0 + bb) * KK + lane] = wt;

    if (lane == 0) {
      gw[bb][0] = w0; gw[bb][1] = w1; gw[bb][2] = w2; gw[bb][3] = w3;
      gi[bb][0] = ti[0]; gi[bb][1] = ti[1]; gi[bb][2] = ti[2]; gi[bb][3] = ti[3];
    }
  }
  __syncthreads();

  // ---- context = weights @ proto (4 sparse rows per batch) ----
#pragma unroll
  for (int bb = 0; bb < 2; ++bb) {
    float w0 = gw[bb][0], w1 = gw[bb][1], w2 = gw[bb][2], w3 = gw[bb][3];
    const float* p0 = proto + (size_t)gi[bb][0] * PD;
    const float* p1 = proto + (size_t)gi[bb][1] * PD;
    const float* p2 = proto + (size_t)gi[bb][2] * PD;
    const float* p3 = proto + (size_t)gi[bb][3] * PD;
    int off = tid * 4;
    float4 r0 = *(const float4*)(p0 + off);
    float4 r1 = *(const float4*)(p1 + off);
    float4 r2 = *(const float4*)(p2 + off);
    float4 r3 = *(const float4*)(p3 + off);
    float4 o;
    o.x = w0 * r0.x + w1 * r1.x + w2 * r2.x + w3 * r3.x;
    o.y = w0 * r0.y + w1 * r1.y + w2 * r2.y + w3 * r3.y;
    o.z = w0 * r0.z + w1 * r1.z + w2 * r2.z + w3 * r3.z;
    o.w = w0 * r0.w + w1 * r1.w + w2 * r2.w + w3 * r3.w;
    *(float4*)(context + (size_t)(b0 + bb) * PD + off) = o;
  }
}

// ---------------------------------------------------------------------------
extern "C" void kernel_launch(void* const* d_in, const int* in_sizes, int n_in,
                              void* d_out, int out_size, void* d_ws,
                              size_t ws_size, hipStream_t stream) {
  const float* hidden = (const float*)d_in[0];
  const float* feat   = (const float*)d_in[1];
  const int*   isl    = (const int*)d_in[2];
  const float* Wf     = (const float*)d_in[3];
  const float* bf     = (const float*)d_in[4];
  const float* W1     = (const float*)d_in[5];
  const float* b1     = (const float*)d_in[6];
  const float* W2     = (const float*)d_in[7];
  const float* b2     = (const float*)d_in[8];
  const float* proto  = (const float*)d_in[9];

  float* out = (float*)d_out;
  float* weights = out;                        // [B,K]
  float* logits  = out + (size_t)BB * KK;      // [B,K]
  float* context = out + (size_t)2 * BB * KK;  // [B,PD]

  float* ws = (float*)d_ws;
  float* part = ws;                                  // SPLIT*B*NF
  float* G1p  = part + (size_t)SPLIT * BB * NF;      // KSPLIT*B*DH (16 MB)

  kernelA<<<GB + BB * SPLIT, 256, 0, stream>>>(hidden, feat, isl, W1, part, G1p);
  stage2_kernel<<<BB / 2, 256, 0, stream>>>(isl, part, Wf, bf, W1, b1, G1p, W2,
                                            b2, proto, weights, logits, context);
}